// Round 1
// baseline (145.258 us; speedup 1.0000x reference)
//
#include <hip/hip_runtime.h>
#include <hip/hip_bf16.h>

// Sizes (fixed by the reference)
#define N_NODES 1024
#define NUM_MOL 32
#define ATOMS 32
#define SDIM 256
#define VDIM 64
#define EDIM 128
#define NBT 5
#define EDGES_PER_MOL (ATOMS * (ATOMS - 1))        // 992
#define PAIRS_PER_MOL (ATOMS * (ATOMS - 1) / 2)    // 496
#define N_PAIRS (NUM_MOL * PAIRS_PER_MOL)          // 15872

// ---------------------------------------------------------------------------
// Kernel 1: s' = silu(s @ W_shared + b_shared)   [1024,256]
// block: 256 threads (one per output channel), 16 rows per block
// ---------------------------------------------------------------------------
#define R1 16
__global__ __launch_bounds__(256) void sprime_kernel(
    const float* __restrict__ s, const float* __restrict__ W,
    const float* __restrict__ b, float* __restrict__ sp)
{
    __shared__ float s_lds[R1][SDIM];
    const int o  = threadIdx.x;
    const int r0 = blockIdx.x * R1;

    for (int r = 0; r < R1; ++r)
        s_lds[r][o] = s[(r0 + r) * SDIM + o];
    __syncthreads();

    float acc[R1];
    const float bo = b[o];
#pragma unroll
    for (int r = 0; r < R1; ++r) acc[r] = bo;

    for (int c = 0; c < SDIM; c += 4) {
        const float w0 = W[(c + 0) * SDIM + o];
        const float w1 = W[(c + 1) * SDIM + o];
        const float w2 = W[(c + 2) * SDIM + o];
        const float w3 = W[(c + 3) * SDIM + o];
#pragma unroll
        for (int r = 0; r < R1; ++r) {
            const float4 sv = *(const float4*)&s_lds[r][c];
            acc[r] += sv.x * w0 + sv.y * w1 + sv.z * w2 + sv.w * w3;
        }
    }
#pragma unroll
    for (int r = 0; r < R1; ++r) {
        const float x = acc[r];
        sp[(r0 + r) * SDIM + o] = x / (1.f + __expf(-x));
    }
}

// ---------------------------------------------------------------------------
// Kernel 2: coords = center_per_mol(p + v @ W_coords)   [1024,3]
// one block per molecule
// ---------------------------------------------------------------------------
__global__ __launch_bounds__(128) void coords_kernel(
    const float* __restrict__ v, const float* __restrict__ p,
    const float* __restrict__ Wc, float* __restrict__ coords)
{
    const int mol = blockIdx.x;
    const int t   = threadIdx.x;
    __shared__ float cl[ATOMS][3];
    __shared__ float mean[3];

    if (t < ATOMS * 3) {
        const int a = t / 3, dim = t % 3;
        const int node = mol * ATOMS + a;
        const float* vv = v + (size_t)node * 3 * VDIM + dim * VDIM;
        float acc = 0.f;
#pragma unroll 8
        for (int k = 0; k < VDIM; ++k) acc += vv[k] * Wc[k];
        cl[a][dim] = p[node * 3 + dim] + acc;
    }
    __syncthreads();
    if (t < 3) {
        float sum = 0.f;
        for (int a = 0; a < ATOMS; ++a) sum += cl[a][t];
        mean[t] = sum * (1.f / ATOMS);
    }
    __syncthreads();
    if (t < ATOMS * 3) {
        const int a = t / 3, dim = t % 3;
        coords[(mol * ATOMS + a) * 3 + dim] = cl[a][dim] - mean[dim];
    }
}

// ---------------------------------------------------------------------------
// Kernel 3: fused per-pair edge MLP.
// One block = TP unordered pairs, 256 threads (thread = channel o).
// out[k] == out[k_rev] by symmetry -> compute once, write twice.
// ---------------------------------------------------------------------------
#define TP 32
__global__ __launch_bounds__(256) void edge_kernel(
    const float* __restrict__ sp, const float* __restrict__ coords,
    const float* __restrict__ e,
    const float* __restrict__ W_bond, const float* __restrict__ b_bond,
    const float* __restrict__ W_b0, const float* __restrict__ b_b0,
    const float* __restrict__ W_b1, const float* __restrict__ b_b1,
    float* __restrict__ out)
{
    __shared__ float e_lds[TP][EDIM];   // 16 KB
    __shared__ float fh[TP][SDIM];      // 32 KB (f, then h)
    __shared__ float dsh[TP];
    __shared__ int   ksh[TP], krevsh[TP], ish[TP], jsh[TP];

    const int o  = threadIdx.x;
    const int P0 = blockIdx.x * TP;

    // ---- decode pairs (threads 0..31, one pair each) ----
    if (o < TP) {
        const int P   = P0 + o;
        const int mol = P / PAIRS_PER_MOL;
        const int p   = P - mol * PAIRS_PER_MOL;
        // O(jj) = (63*jj - jj*jj)/2 ; find max jj with O(jj) <= p
        int jj = (int)((63.0f - sqrtf((float)(3969 - 8 * p))) * 0.5f);
        if (jj < 0) jj = 0;
        if (jj > 30) jj = 30;
        while (jj > 0 && (63 * jj - jj * jj) / 2 > p) --jj;
        while (jj < 30 && (63 * (jj + 1) - (jj + 1) * (jj + 1)) / 2 <= p) ++jj;
        const int Ojj = (63 * jj - jj * jj) / 2;
        const int ii  = jj + 1 + (p - Ojj);          // jj < ii
        const int q    = jj * 31 + (ii - 1);
        const int qrev = ii * 31 + jj;
        const int k    = mol * EDGES_PER_MOL + q;
        const int krev = mol * EDGES_PER_MOL + qrev;
        const int i = mol * ATOMS + ii, j = mol * ATOMS + jj;
        ksh[o] = k; krevsh[o] = krev; ish[o] = i; jsh[o] = j;
        const float dx = coords[i * 3 + 0] - coords[j * 3 + 0];
        const float dy = coords[i * 3 + 1] - coords[j * 3 + 1];
        const float dz = coords[i * 3 + 2] - coords[j * 3 + 2];
        dsh[o] = dx * dx + dy * dy + dz * dz;
    }
    __syncthreads();

    // ---- stage e_sym tile: 0.5*(e[k] + e[krev]) ----
    {
        const int rr = o >> 7;        // 0..1
        const int c  = o & 127;
        for (int r = rr; r < TP; r += 2) {
            e_lds[r][c] = 0.5f * (e[(size_t)ksh[r] * EDIM + c] +
                                  e[(size_t)krevsh[r] * EDIM + c]);
        }
    }
    __syncthreads();

    float acc[TP];

    // ---- f-stage: f[r][o] = s'[i]+s'[j]+b_bond[o] + e_sym[r,:] @ W_bond[:,o] ----
    {
        const float bo = b_bond[o];
#pragma unroll
        for (int r = 0; r < TP; ++r)
            acc[r] = sp[(size_t)ish[r] * SDIM + o] +
                     sp[(size_t)jsh[r] * SDIM + o] + bo;

        for (int c = 0; c < EDIM; c += 4) {
            const float w0 = W_bond[(c + 0) * SDIM + o];
            const float w1 = W_bond[(c + 1) * SDIM + o];
            const float w2 = W_bond[(c + 2) * SDIM + o];
            const float w3 = W_bond[(c + 3) * SDIM + o];
#pragma unroll
            for (int r = 0; r < TP; ++r) {
                const float4 ev = *(const float4*)&e_lds[r][c];
                acc[r] += ev.x * w0 + ev.y * w1 + ev.z * w2 + ev.w * w3;
            }
        }
#pragma unroll
        for (int r = 0; r < TP; ++r) fh[r][o] = acc[r];
    }
    __syncthreads();

    // ---- h-stage: h[r][o] = silu(f[r,:] @ W_b0[0:256,o] + d[r]*W_b0[256,o] + b_b0[o]) ----
    {
        const float w256 = W_b0[256 * SDIM + o];
        const float bo   = b_b0[o];
#pragma unroll
        for (int r = 0; r < TP; ++r) acc[r] = dsh[r] * w256 + bo;

        for (int c = 0; c < SDIM; c += 4) {
            const float w0 = W_b0[(c + 0) * SDIM + o];
            const float w1 = W_b0[(c + 1) * SDIM + o];
            const float w2 = W_b0[(c + 2) * SDIM + o];
            const float w3 = W_b0[(c + 3) * SDIM + o];
#pragma unroll
            for (int r = 0; r < TP; ++r) {
                const float4 fv = *(const float4*)&fh[r][c];
                acc[r] += fv.x * w0 + fv.y * w1 + fv.z * w2 + fv.w * w3;
            }
        }
        __syncthreads();   // everyone finished reading f
#pragma unroll
        for (int r = 0; r < TP; ++r) {
            const float x = acc[r];
            fh[r][o] = x / (1.f + __expf(-x));
        }
    }
    __syncthreads();

    // ---- final: out[k][t] = h[r,:] @ W_b1[:,t] + b_b1[t]  (write k and krev) ----
    if (o < TP * NBT) {
        const int r = o / NBT, t = o - (o / NBT) * NBT;
        float accf = b_b1[t];
        for (int cc = 0; cc < SDIM / 4; ++cc) {
            const int c = ((cc + r * 2) & (SDIM / 4 - 1)) * 4;  // bank skew
            const float4 hv = *(const float4*)&fh[r][c];
            accf += hv.x * W_b1[(c + 0) * NBT + t] + hv.y * W_b1[(c + 1) * NBT + t] +
                    hv.z * W_b1[(c + 2) * NBT + t] + hv.w * W_b1[(c + 3) * NBT + t];
        }
        out[(size_t)ksh[r] * NBT + t]    = accf;
        out[(size_t)krevsh[r] * NBT + t] = accf;
    }
}

// ---------------------------------------------------------------------------
extern "C" void kernel_launch(void* const* d_in, const int* in_sizes, int n_in,
                              void* d_out, int out_size, void* d_ws, size_t ws_size,
                              hipStream_t stream)
{
    const float* s        = (const float*)d_in[0];
    const float* v        = (const float*)d_in[1];
    const float* p        = (const float*)d_in[2];
    const float* e        = (const float*)d_in[3];
    // d_in[4] = batch (unused, analytic), d_in[5] = edge_index (unused, analytic)
    const float* W_shared = (const float*)d_in[6];
    const float* b_shared = (const float*)d_in[7];
    const float* W_coords = (const float*)d_in[8];
    const float* W_bond   = (const float*)d_in[9];
    const float* b_bond   = (const float*)d_in[10];
    const float* W_b0     = (const float*)d_in[11];
    const float* b_b0     = (const float*)d_in[12];
    const float* W_b1     = (const float*)d_in[13];
    const float* b_b1     = (const float*)d_in[14];
    float* out = (float*)d_out;

    float* sp     = (float*)d_ws;                    // [1024,256] = 1 MB
    float* coords = sp + (size_t)N_NODES * SDIM;     // [1024,3]

    sprime_kernel<<<N_NODES / R1, 256, 0, stream>>>(s, W_shared, b_shared, sp);
    coords_kernel<<<NUM_MOL, 128, 0, stream>>>(v, p, W_coords, coords);
    edge_kernel<<<N_PAIRS / TP, 256, 0, stream>>>(sp, coords, e,
                                                  W_bond, b_bond, W_b0, b_b0,
                                                  W_b1, b_b1, out);
}

// Round 2
// 83.339 us; speedup vs baseline: 1.7430x; 1.7430x over previous
//
#include <hip/hip_runtime.h>
#include <hip/hip_bf16.h>

// Sizes (fixed by the reference)
#define N_NODES 1024
#define NUM_MOL 32
#define ATOMS 32
#define SDIM 256
#define VDIM 64
#define EDIM 128
#define NBT 5
#define EDGES_PER_MOL (ATOMS * (ATOMS - 1))        // 992
#define PAIRS_PER_MOL (ATOMS * (ATOMS - 1) / 2)    // 496
#define N_PAIRS (NUM_MOL * PAIRS_PER_MOL)          // 15872

typedef __attribute__((ext_vector_type(8))) short bf16x8;
typedef __attribute__((ext_vector_type(4))) float f32x4;

__device__ __forceinline__ unsigned short f2bf(float x) {
    union { float f; unsigned int u; } v; v.f = x;
    unsigned int r = v.u + 0x7fffu + ((v.u >> 16) & 1u);
    return (unsigned short)(r >> 16);
}

// ---------------------------------------------------------------------------
// Kernel A: sp2 = silu(s @ W_shared + b_shared) @ W_b0[0:256,:]   [1024,256]
// ---------------------------------------------------------------------------
#define RA 8
__global__ __launch_bounds__(256) void node_kernel(
    const float* __restrict__ s, const float* __restrict__ Ws,
    const float* __restrict__ bs, const float* __restrict__ Wb0,
    float* __restrict__ sp2)
{
    __shared__ float sl[RA][SDIM];
    const int o  = threadIdx.x;
    const int r0 = blockIdx.x * RA;

    for (int r = 0; r < RA; ++r) sl[r][o] = s[(r0 + r) * SDIM + o];
    __syncthreads();

    float acc[RA];
    const float bo = bs[o];
#pragma unroll
    for (int r = 0; r < RA; ++r) acc[r] = bo;

    for (int c = 0; c < SDIM; c += 4) {
        const float w0 = Ws[(c + 0) * SDIM + o];
        const float w1 = Ws[(c + 1) * SDIM + o];
        const float w2 = Ws[(c + 2) * SDIM + o];
        const float w3 = Ws[(c + 3) * SDIM + o];
#pragma unroll
        for (int r = 0; r < RA; ++r) {
            const float4 sv = *(const float4*)&sl[r][c];
            acc[r] += sv.x * w0 + sv.y * w1 + sv.z * w2 + sv.w * w3;
        }
    }
    __syncthreads();          // all reads of sl done before overwrite
#pragma unroll
    for (int r = 0; r < RA; ++r) {
        const float x = acc[r];
        sl[r][o] = x / (1.f + __expf(-x));   // s'
    }
    __syncthreads();

    float a2[RA];
#pragma unroll
    for (int r = 0; r < RA; ++r) a2[r] = 0.f;

    for (int c = 0; c < SDIM; c += 4) {
        const float w0 = Wb0[(c + 0) * SDIM + o];
        const float w1 = Wb0[(c + 1) * SDIM + o];
        const float w2 = Wb0[(c + 2) * SDIM + o];
        const float w3 = Wb0[(c + 3) * SDIM + o];
#pragma unroll
        for (int r = 0; r < RA; ++r) {
            const float4 sv = *(const float4*)&sl[r][c];
            a2[r] += sv.x * w0 + sv.y * w1 + sv.z * w2 + sv.w * w3;
        }
    }
#pragma unroll
    for (int r = 0; r < RA; ++r) sp2[(r0 + r) * SDIM + o] = a2[r];
}

// ---------------------------------------------------------------------------
// Kernel B: coords = center_per_mol(p + v @ W_coords)   [1024,3]
// ---------------------------------------------------------------------------
__global__ __launch_bounds__(128) void coords_kernel(
    const float* __restrict__ v, const float* __restrict__ p,
    const float* __restrict__ Wc, float* __restrict__ coords)
{
    const int mol = blockIdx.x;
    const int t   = threadIdx.x;
    __shared__ float cl[ATOMS][3];
    __shared__ float mean[3];

    if (t < ATOMS * 3) {
        const int a = t / 3, dim = t % 3;
        const int node = mol * ATOMS + a;
        const float* vv = v + (size_t)node * 3 * VDIM + dim * VDIM;
        float acc = 0.f;
#pragma unroll 8
        for (int k = 0; k < VDIM; ++k) acc += vv[k] * Wc[k];
        cl[a][dim] = p[node * 3 + dim] + acc;
    }
    __syncthreads();
    if (t < 3) {
        float sum = 0.f;
        for (int a = 0; a < ATOMS; ++a) sum += cl[a][t];
        mean[t] = sum * (1.f / ATOMS);
    }
    __syncthreads();
    if (t < ATOMS * 3) {
        const int a = t / 3, dim = t % 3;
        coords[(mol * ATOMS + a) * 3 + dim] = cl[a][dim] - mean[dim];
    }
}

// ---------------------------------------------------------------------------
// Kernel C: prep.
//  blocks 0..7: W_comb = 0.5 * (W_bond @ W_b0[0:256,:]) -> bf16, scattered into
//               exact MFMA B-fragment order: elem(k,n) at
//               Wf[((nt*4+kt)*64 + lane)*8 + e], lane = (n&15)+16*((k>>3)&3),
//               nt = n>>4, kt = k>>5, e = k&7.
//  block 8:     b_comb = b_bond @ W_b0[0:256,:] + b_b0
// ---------------------------------------------------------------------------
__global__ __launch_bounds__(256) void prep_kernel(
    const float* __restrict__ Wbond, const float* __restrict__ bbond,
    const float* __restrict__ Wb0, const float* __restrict__ bb0,
    unsigned short* __restrict__ Wf, float* __restrict__ bcomb)
{
    const int o = threadIdx.x;
    if (blockIdx.x == 8) {
        float acc = bb0[o];
        for (int m = 0; m < SDIM; ++m) acc += bbond[m] * Wb0[m * SDIM + o];
        bcomb[o] = acc;
        return;
    }
    __shared__ float wb[16][SDIM];
    const int r0 = blockIdx.x * 16;
    for (int r = 0; r < 16; ++r) wb[r][o] = Wbond[(r0 + r) * SDIM + o];
    __syncthreads();

    float acc[16];
#pragma unroll
    for (int r = 0; r < 16; ++r) acc[r] = 0.f;

    for (int c = 0; c < SDIM; c += 4) {
        const float w0 = Wb0[(c + 0) * SDIM + o];
        const float w1 = Wb0[(c + 1) * SDIM + o];
        const float w2 = Wb0[(c + 2) * SDIM + o];
        const float w3 = Wb0[(c + 3) * SDIM + o];
#pragma unroll
        for (int r = 0; r < 16; ++r) {
            const float4 wv = *(const float4*)&wb[r][c];
            acc[r] += wv.x * w0 + wv.y * w1 + wv.z * w2 + wv.w * w3;
        }
    }
    const int nt = o >> 4;
#pragma unroll
    for (int r = 0; r < 16; ++r) {
        const int k = r0 + r;
        const int kt = k >> 5, g = (k >> 3) & 3, eidx = k & 7;
        const int lane = (o & 15) + 16 * g;
        Wf[((size_t)((nt * 4 + kt) * 64 + lane)) * 8 + eidx] = f2bf(0.5f * acc[r]);
    }
}

// ---------------------------------------------------------------------------
// Kernel D: edge MFMA kernel. Block = 64 pairs, 256 threads = 4 waves.
// Wave w computes rows [w*16, w*16+16) x all 256 cols via 16x16x32 bf16 MFMA.
// hpre = e_sym @ W_comb  (MFMA)  + spsum (exact f32: sp2_i + sp2_j + d*w256 + b_comb)
// h = silu(hpre);  out = h @ W_b1 + b_b1  (f32 VALU), written to k and krev.
// ---------------------------------------------------------------------------
#define RP 64
__global__ __launch_bounds__(256) void edge_mfma_kernel(
    const float* __restrict__ sp2, const float* __restrict__ coords,
    const float* __restrict__ e, const unsigned short* __restrict__ Wf,
    const float* __restrict__ bcomb, const float* __restrict__ Wb0,
    const float* __restrict__ Wb1, const float* __restrict__ bb1,
    float* __restrict__ out)
{
    __shared__ float spsum[RP][260];       // stride 260 floats (16B aligned rows)
    __shared__ int   ksh[RP], krevsh[RP], ish[RP], jsh[RP];
    __shared__ float dsh[RP];

    const int t  = threadIdx.x;
    const int P0 = blockIdx.x * RP;

    // ---- decode pairs ----
    if (t < RP) {
        const int P   = P0 + t;
        const int mol = P / PAIRS_PER_MOL;
        const int p   = P - mol * PAIRS_PER_MOL;
        int jj = (int)((63.0f - sqrtf((float)(3969 - 8 * p))) * 0.5f);
        if (jj < 0) jj = 0;
        if (jj > 30) jj = 30;
        while (jj > 0 && (63 * jj - jj * jj) / 2 > p) --jj;
        while (jj < 30 && (63 * (jj + 1) - (jj + 1) * (jj + 1)) / 2 <= p) ++jj;
        const int Ojj = (63 * jj - jj * jj) / 2;
        const int ii  = jj + 1 + (p - Ojj);
        const int q    = jj * 31 + (ii - 1);
        const int qrev = ii * 31 + jj;
        ksh[t]    = mol * EDGES_PER_MOL + q;
        krevsh[t] = mol * EDGES_PER_MOL + qrev;
        const int i = mol * ATOMS + ii, j = mol * ATOMS + jj;
        ish[t] = i; jsh[t] = j;
        const float dx = coords[i * 3 + 0] - coords[j * 3 + 0];
        const float dy = coords[i * 3 + 1] - coords[j * 3 + 1];
        const float dz = coords[i * 3 + 2] - coords[j * 3 + 2];
        dsh[t] = dx * dx + dy * dy + dz * dz;
    }
    __syncthreads();

    // ---- spsum fill (stride-4 scalar: conflict-free LDS writes) ----
    {
        const int r  = t >> 2, c0 = t & 3;
        const float* ai = sp2 + (size_t)ish[r] * SDIM;
        const float* aj = sp2 + (size_t)jsh[r] * SDIM;
        const float* w2 = Wb0 + (size_t)SDIM * SDIM;   // row 256 of W_b0
        const float d = dsh[r];
        for (int i = 0; i < 64; ++i) {
            const int c = c0 + 4 * i;
            spsum[r][c] = ai[c] + aj[c] + d * w2[c] + bcomb[c];
        }
    }
    __syncthreads();

    // ---- MFMA: per wave, A = e_sym rows (16x128), B = W_comb (128x256) ----
    const int w = t >> 6, l = t & 63;
    const int lr = w * 16 + (l & 15);
    const float* ek  = e + (size_t)ksh[lr] * EDIM + 8 * (l >> 4);
    const float* ekr = e + (size_t)krevsh[lr] * EDIM + 8 * (l >> 4);

    bf16x8 afrag[4];
#pragma unroll
    for (int kt = 0; kt < 4; ++kt) {
        const float4 x0 = *(const float4*)(ek + kt * 32);
        const float4 x1 = *(const float4*)(ek + kt * 32 + 4);
        const float4 y0 = *(const float4*)(ekr + kt * 32);
        const float4 y1 = *(const float4*)(ekr + kt * 32 + 4);
        afrag[kt][0] = (short)f2bf(x0.x + y0.x);
        afrag[kt][1] = (short)f2bf(x0.y + y0.y);
        afrag[kt][2] = (short)f2bf(x0.z + y0.z);
        afrag[kt][3] = (short)f2bf(x0.w + y0.w);
        afrag[kt][4] = (short)f2bf(x1.x + y1.x);
        afrag[kt][5] = (short)f2bf(x1.y + y1.y);
        afrag[kt][6] = (short)f2bf(x1.z + y1.z);
        afrag[kt][7] = (short)f2bf(x1.w + y1.w);
    }

    f32x4 acc[16];
#pragma unroll
    for (int nt = 0; nt < 16; ++nt) { acc[nt][0] = 0.f; acc[nt][1] = 0.f; acc[nt][2] = 0.f; acc[nt][3] = 0.f; }

    const bf16x8* wfp = (const bf16x8*)Wf;
#pragma unroll
    for (int nt = 0; nt < 16; ++nt) {
        const bf16x8 b0 = wfp[(nt * 4 + 0) * 64 + l];
        const bf16x8 b1 = wfp[(nt * 4 + 1) * 64 + l];
        const bf16x8 b2 = wfp[(nt * 4 + 2) * 64 + l];
        const bf16x8 b3 = wfp[(nt * 4 + 3) * 64 + l];
        acc[nt] = __builtin_amdgcn_mfma_f32_16x16x32_bf16(afrag[0], b0, acc[nt], 0, 0, 0);
        acc[nt] = __builtin_amdgcn_mfma_f32_16x16x32_bf16(afrag[1], b1, acc[nt], 0, 0, 0);
        acc[nt] = __builtin_amdgcn_mfma_f32_16x16x32_bf16(afrag[2], b2, acc[nt], 0, 0, 0);
        acc[nt] = __builtin_amdgcn_mfma_f32_16x16x32_bf16(afrag[3], b3, acc[nt], 0, 0, 0);
    }

    // ---- epilogue: h = silu(acc + spsum), written back into spsum ----
    // D layout (HW-verified): col = nt*16 + (l&15), row = 4*(l>>4) + reg
#pragma unroll
    for (int nt = 0; nt < 16; ++nt) {
#pragma unroll
        for (int j = 0; j < 4; ++j) {
            const int r = w * 16 + (l >> 4) * 4 + j;
            const int n = nt * 16 + (l & 15);
            const float x = acc[nt][j] + spsum[r][n];
            spsum[r][n] = x / (1.f + __expf(-x));
        }
    }
    __syncthreads();

    // ---- final: out = h @ W_b1 + b_b1, write k and krev ----
    for (int task = t; task < RP * NBT; task += 256) {
        const int r  = task / NBT;
        const int tt = task - r * NBT;
        float a = bb1[tt];
        for (int c = 0; c < SDIM; c += 4) {
            const float4 hv = *(const float4*)&spsum[r][c];
            a += hv.x * Wb1[(c + 0) * NBT + tt] + hv.y * Wb1[(c + 1) * NBT + tt] +
                 hv.z * Wb1[(c + 2) * NBT + tt] + hv.w * Wb1[(c + 3) * NBT + tt];
        }
        out[(size_t)ksh[r] * NBT + tt]    = a;
        out[(size_t)krevsh[r] * NBT + tt] = a;
    }
}

// ---------------------------------------------------------------------------
extern "C" void kernel_launch(void* const* d_in, const int* in_sizes, int n_in,
                              void* d_out, int out_size, void* d_ws, size_t ws_size,
                              hipStream_t stream)
{
    const float* s        = (const float*)d_in[0];
    const float* v        = (const float*)d_in[1];
    const float* p        = (const float*)d_in[2];
    const float* e        = (const float*)d_in[3];
    const float* W_shared = (const float*)d_in[6];
    const float* b_shared = (const float*)d_in[7];
    const float* W_coords = (const float*)d_in[8];
    const float* W_bond   = (const float*)d_in[9];
    const float* b_bond   = (const float*)d_in[10];
    const float* W_b0     = (const float*)d_in[11];
    const float* b_b0     = (const float*)d_in[12];
    const float* W_b1     = (const float*)d_in[13];
    const float* b_b1     = (const float*)d_in[14];
    float* out = (float*)d_out;

    float* sp2    = (float*)d_ws;                           // 262144 f32 (1 MB)
    float* coords = sp2 + (size_t)N_NODES * SDIM;           // 3072 f32
    unsigned short* Wf = (unsigned short*)(coords + 3072);  // 32768 bf16 (64 KB)
    float* bcomb  = (float*)((char*)Wf + 65536);            // 256 f32

    node_kernel<<<N_NODES / RA, 256, 0, stream>>>(s, W_shared, b_shared, W_b0, sp2);
    coords_kernel<<<NUM_MOL, 128, 0, stream>>>(v, p, W_coords, coords);
    prep_kernel<<<9, 256, 0, stream>>>(W_bond, b_bond, W_b0, b_b0, Wf, bcomb);
    edge_mfma_kernel<<<N_PAIRS / RP, 256, 0, stream>>>(sp2, coords, e, Wf, bcomb,
                                                       W_b0, W_b1, b_b1, out);
}

// Round 3
// 62.324 us; speedup vs baseline: 2.3307x; 1.3372x over previous
//
#include <hip/hip_runtime.h>
#include <hip/hip_bf16.h>

// Sizes (fixed by the reference)
#define N_NODES 1024
#define NUM_MOL 32
#define ATOMS 32
#define SDIM 256
#define VDIM 64
#define EDIM 128
#define NBT 5
#define EDGES_PER_MOL (ATOMS * (ATOMS - 1))        // 992
#define PAIRS_PER_MOL (ATOMS * (ATOMS - 1) / 2)    // 496
#define N_PAIRS (NUM_MOL * PAIRS_PER_MOL)          // 15872

typedef __attribute__((ext_vector_type(8))) short bf16x8;
typedef __attribute__((ext_vector_type(4))) float f32x4;

__device__ __forceinline__ unsigned short f2bf(float x) {
    union { float f; unsigned int u; } v; v.f = x;
    unsigned int r = v.u + 0x7fffu + ((v.u >> 16) & 1u);
    return (unsigned short)(r >> 16);
}

// ---------------------------------------------------------------------------
// Fused misc kernel: grid = 128 (node) + 32 (coords) + 9 (prep) = 169 blocks.
//  node  (bid 0..127):  sp2 = silu(s @ W_shared + b_shared) @ W_b0[0:256,:]
//  coords(bid 128..159): coords = center_per_mol(p + v @ W_coords)
//  prep  (bid 160..167): W_comb = 0.5*(W_bond @ W_b0) -> bf16 MFMA-B-fragment order
//  prep  (bid 168):      b_comb = b_bond @ W_b0 + b_b0
// ---------------------------------------------------------------------------
#define RA 8
__global__ __launch_bounds__(256) void misc_kernel(
    const float* __restrict__ s, const float* __restrict__ Ws,
    const float* __restrict__ bs, const float* __restrict__ Wb0,
    const float* __restrict__ v, const float* __restrict__ p,
    const float* __restrict__ Wc,
    const float* __restrict__ Wbond, const float* __restrict__ bbond,
    const float* __restrict__ bb0,
    float* __restrict__ sp2, float* __restrict__ coords,
    unsigned short* __restrict__ Wf, float* __restrict__ bcomb)
{
    __shared__ __align__(16) float smem[16 * SDIM];   // 16 KB union
    const int o   = threadIdx.x;
    const int bid = blockIdx.x;

    if (bid < 128) {
        // ---------------- node ----------------
        float (*sl)[SDIM] = (float (*)[SDIM])smem;
        const int r0 = bid * RA;
        for (int r = 0; r < RA; ++r) sl[r][o] = s[(r0 + r) * SDIM + o];
        __syncthreads();

        float acc[RA];
        const float bo = bs[o];
#pragma unroll
        for (int r = 0; r < RA; ++r) acc[r] = bo;
        for (int c = 0; c < SDIM; c += 4) {
            const float w0 = Ws[(c + 0) * SDIM + o];
            const float w1 = Ws[(c + 1) * SDIM + o];
            const float w2 = Ws[(c + 2) * SDIM + o];
            const float w3 = Ws[(c + 3) * SDIM + o];
#pragma unroll
            for (int r = 0; r < RA; ++r) {
                const float4 sv = *(const float4*)&sl[r][c];
                acc[r] += sv.x * w0 + sv.y * w1 + sv.z * w2 + sv.w * w3;
            }
        }
        __syncthreads();
#pragma unroll
        for (int r = 0; r < RA; ++r) {
            const float x = acc[r];
            sl[r][o] = x / (1.f + __expf(-x));
        }
        __syncthreads();

        float a2[RA];
#pragma unroll
        for (int r = 0; r < RA; ++r) a2[r] = 0.f;
        for (int c = 0; c < SDIM; c += 4) {
            const float w0 = Wb0[(c + 0) * SDIM + o];
            const float w1 = Wb0[(c + 1) * SDIM + o];
            const float w2 = Wb0[(c + 2) * SDIM + o];
            const float w3 = Wb0[(c + 3) * SDIM + o];
#pragma unroll
            for (int r = 0; r < RA; ++r) {
                const float4 sv = *(const float4*)&sl[r][c];
                a2[r] += sv.x * w0 + sv.y * w1 + sv.z * w2 + sv.w * w3;
            }
        }
#pragma unroll
        for (int r = 0; r < RA; ++r) sp2[(r0 + r) * SDIM + o] = a2[r];

    } else if (bid < 160) {
        // ---------------- coords ----------------
        const int mol = bid - 128;
        float* cl   = smem;            // [32][3]
        float* mean = smem + 100;
        if (o < ATOMS * 3) {
            const int a = o / 3, dim = o % 3;
            const int node = mol * ATOMS + a;
            const float* vv = v + (size_t)node * 3 * VDIM + dim * VDIM;
            float acc = 0.f;
#pragma unroll 8
            for (int k = 0; k < VDIM; ++k) acc += vv[k] * Wc[k];
            cl[a * 3 + dim] = p[node * 3 + dim] + acc;
        }
        __syncthreads();
        if (o < 3) {
            float sum = 0.f;
            for (int a = 0; a < ATOMS; ++a) sum += cl[a * 3 + o];
            mean[o] = sum * (1.f / ATOMS);
        }
        __syncthreads();
        if (o < ATOMS * 3) {
            const int a = o / 3, dim = o % 3;
            coords[(mol * ATOMS + a) * 3 + dim] = cl[a * 3 + dim] - mean[dim];
        }

    } else if (bid < 168) {
        // ---------------- prep: W_comb -> MFMA B fragments ----------------
        float (*wb)[SDIM] = (float (*)[SDIM])smem;
        const int r0 = (bid - 160) * 16;
        for (int r = 0; r < 16; ++r) wb[r][o] = Wbond[(r0 + r) * SDIM + o];
        __syncthreads();

        float acc[16];
#pragma unroll
        for (int r = 0; r < 16; ++r) acc[r] = 0.f;
        for (int c = 0; c < SDIM; c += 4) {
            const float w0 = Wb0[(c + 0) * SDIM + o];
            const float w1 = Wb0[(c + 1) * SDIM + o];
            const float w2 = Wb0[(c + 2) * SDIM + o];
            const float w3 = Wb0[(c + 3) * SDIM + o];
#pragma unroll
            for (int r = 0; r < 16; ++r) {
                const float4 wv = *(const float4*)&wb[r][c];
                acc[r] += wv.x * w0 + wv.y * w1 + wv.z * w2 + wv.w * w3;
            }
        }
        const int nt = o >> 4;
#pragma unroll
        for (int r = 0; r < 16; ++r) {
            const int k = r0 + r;
            const int kt = k >> 5, g = (k >> 3) & 3, eidx = k & 7;
            const int lane = (o & 15) + 16 * g;
            Wf[((size_t)((nt * 4 + kt) * 64 + lane)) * 8 + eidx] = f2bf(0.5f * acc[r]);
        }
    } else {
        // ---------------- prep: b_comb ----------------
        float acc = bb0[o];
        for (int m = 0; m < SDIM; ++m) acc += bbond[m] * Wb0[m * SDIM + o];
        bcomb[o] = acc;
    }
}

// ---------------------------------------------------------------------------
// Edge kernel: block = 16 pairs, 256 threads = 4 waves.
// Wave w computes all 16 rows x cols [w*64, w*64+64) via 4x(4 MFMA) 16x16x32.
// hpre = e_sym @ W_comb (MFMA) + spsum (f32: sp2_i + sp2_j + d*w256 + b_comb)
// h = silu(hpre); out = h @ W_b1 + b_b1 (f32), written to k and krev.
// ---------------------------------------------------------------------------
#define PB 16
__global__ __launch_bounds__(256) void edge_mfma_kernel(
    const float* __restrict__ sp2, const float* __restrict__ coords,
    const float* __restrict__ e, const unsigned short* __restrict__ Wf,
    const float* __restrict__ bcomb, const float* __restrict__ Wb0,
    const float* __restrict__ Wb1, const float* __restrict__ bb1,
    float* __restrict__ out)
{
    __shared__ __align__(16) float spsum[PB][260];   // 16.6 KB
    __shared__ int   ksh[PB], krevsh[PB], ish[PB], jsh[PB];
    __shared__ float dsh[PB];

    const int t  = threadIdx.x;
    const int P0 = blockIdx.x * PB;

    // ---- decode pairs (threads 0..15) ----
    if (t < PB) {
        const int P   = P0 + t;
        const int mol = P / PAIRS_PER_MOL;
        const int p   = P - mol * PAIRS_PER_MOL;
        int jj = (int)((63.0f - sqrtf((float)(3969 - 8 * p))) * 0.5f);
        if (jj < 0) jj = 0;
        if (jj > 30) jj = 30;
        while (jj > 0 && (63 * jj - jj * jj) / 2 > p) --jj;
        while (jj < 30 && (63 * (jj + 1) - (jj + 1) * (jj + 1)) / 2 <= p) ++jj;
        const int Ojj = (63 * jj - jj * jj) / 2;
        const int ii  = jj + 1 + (p - Ojj);
        const int q    = jj * 31 + (ii - 1);
        const int qrev = ii * 31 + jj;
        ksh[t]    = mol * EDGES_PER_MOL + q;
        krevsh[t] = mol * EDGES_PER_MOL + qrev;
        const int i = mol * ATOMS + ii, j = mol * ATOMS + jj;
        ish[t] = i; jsh[t] = j;
        const float dx = coords[i * 3 + 0] - coords[j * 3 + 0];
        const float dy = coords[i * 3 + 1] - coords[j * 3 + 1];
        const float dz = coords[i * 3 + 2] - coords[j * 3 + 2];
        dsh[t] = dx * dx + dy * dy + dz * dz;
    }
    __syncthreads();

    // ---- spsum fill: row = t>>4, lane-contiguous float4 (conflict-free) ----
    {
        const int r  = t >> 4;
        const int c0 = (t & 15) * 4;
        const float* ai = sp2 + (size_t)ish[r] * SDIM;
        const float* aj = sp2 + (size_t)jsh[r] * SDIM;
        const float* w2 = Wb0 + (size_t)SDIM * SDIM;   // row 256 of W_b0
        const float d = dsh[r];
#pragma unroll
        for (int i = 0; i < 4; ++i) {
            const int c = c0 + 64 * i;
            const float4 a4 = *(const float4*)(ai + c);
            const float4 b4 = *(const float4*)(aj + c);
            const float4 w4 = *(const float4*)(w2 + c);
            const float4 g4 = *(const float4*)(bcomb + c);
            float4 rv;
            rv.x = a4.x + b4.x + d * w4.x + g4.x;
            rv.y = a4.y + b4.y + d * w4.y + g4.y;
            rv.z = a4.z + b4.z + d * w4.z + g4.z;
            rv.w = a4.w + b4.w + d * w4.w + g4.w;
            *(float4*)&spsum[r][c] = rv;
        }
    }
    __syncthreads();

    const int w = t >> 6, l = t & 63;
    const int lr = l & 15;

    // ---- A fragments: e_sym rows (identical across waves -> L1 hits) ----
    const float* ek  = e + (size_t)ksh[lr] * EDIM + 8 * (l >> 4);
    const float* ekr = e + (size_t)krevsh[lr] * EDIM + 8 * (l >> 4);
    bf16x8 afrag[4];
#pragma unroll
    for (int kt = 0; kt < 4; ++kt) {
        const float4 x0 = *(const float4*)(ek + kt * 32);
        const float4 x1 = *(const float4*)(ek + kt * 32 + 4);
        const float4 y0 = *(const float4*)(ekr + kt * 32);
        const float4 y1 = *(const float4*)(ekr + kt * 32 + 4);
        afrag[kt][0] = (short)f2bf(x0.x + y0.x);
        afrag[kt][1] = (short)f2bf(x0.y + y0.y);
        afrag[kt][2] = (short)f2bf(x0.z + y0.z);
        afrag[kt][3] = (short)f2bf(x0.w + y0.w);
        afrag[kt][4] = (short)f2bf(x1.x + y1.x);
        afrag[kt][5] = (short)f2bf(x1.y + y1.y);
        afrag[kt][6] = (short)f2bf(x1.z + y1.z);
        afrag[kt][7] = (short)f2bf(x1.w + y1.w);
    }

    // ---- MFMA: wave w covers col tiles nt = 4w .. 4w+3 ----
    const bf16x8* wfp = (const bf16x8*)Wf;
    f32x4 acc[4];
#pragma unroll
    for (int q = 0; q < 4; ++q) {
        acc[q][0] = 0.f; acc[q][1] = 0.f; acc[q][2] = 0.f; acc[q][3] = 0.f;
        const int nt = w * 4 + q;
        const bf16x8 b0 = wfp[(nt * 4 + 0) * 64 + l];
        const bf16x8 b1 = wfp[(nt * 4 + 1) * 64 + l];
        const bf16x8 b2 = wfp[(nt * 4 + 2) * 64 + l];
        const bf16x8 b3 = wfp[(nt * 4 + 3) * 64 + l];
        acc[q] = __builtin_amdgcn_mfma_f32_16x16x32_bf16(afrag[0], b0, acc[q], 0, 0, 0);
        acc[q] = __builtin_amdgcn_mfma_f32_16x16x32_bf16(afrag[1], b1, acc[q], 0, 0, 0);
        acc[q] = __builtin_amdgcn_mfma_f32_16x16x32_bf16(afrag[2], b2, acc[q], 0, 0, 0);
        acc[q] = __builtin_amdgcn_mfma_f32_16x16x32_bf16(afrag[3], b3, acc[q], 0, 0, 0);
    }

    // ---- epilogue: h = silu(acc + spsum) back into spsum ----
    // D layout: col = nt*16 + (l&15), row = 4*(l>>4) + j
#pragma unroll
    for (int q = 0; q < 4; ++q) {
        const int n = (w * 4 + q) * 16 + (l & 15);
#pragma unroll
        for (int j = 0; j < 4; ++j) {
            const int r = (l >> 4) * 4 + j;
            const float x = acc[q][j] + spsum[r][n];
            spsum[r][n] = x / (1.f + __expf(-x));
        }
    }
    __syncthreads();

    // ---- final: out = h @ W_b1 + b_b1 ; 2 threads per (pair, bondtype) ----
    if (t < PB * NBT * 2) {
        const int task = t >> 1, half = t & 1;
        const int r  = task / NBT;
        const int tt = task - r * NBT;
        float a = half ? 0.f : bb1[tt];
        const int base = half * 32;            // float4 index offset
#pragma unroll 4
        for (int cc = 0; cc < 32; ++cc) {
            const int c4 = base + ((cc + task) & 31);
            const int c  = c4 * 4;
            const float4 hv = *(const float4*)&spsum[r][c];
            a += hv.x * Wb1[(c + 0) * NBT + tt] + hv.y * Wb1[(c + 1) * NBT + tt] +
                 hv.z * Wb1[(c + 2) * NBT + tt] + hv.w * Wb1[(c + 3) * NBT + tt];
        }
        a += __shfl_xor(a, 1);
        if (!half) {
            out[(size_t)ksh[r] * NBT + tt]    = a;
            out[(size_t)krevsh[r] * NBT + tt] = a;
        }
    }
}

// ---------------------------------------------------------------------------
extern "C" void kernel_launch(void* const* d_in, const int* in_sizes, int n_in,
                              void* d_out, int out_size, void* d_ws, size_t ws_size,
                              hipStream_t stream)
{
    const float* s        = (const float*)d_in[0];
    const float* v        = (const float*)d_in[1];
    const float* p        = (const float*)d_in[2];
    const float* e        = (const float*)d_in[3];
    const float* W_shared = (const float*)d_in[6];
    const float* b_shared = (const float*)d_in[7];
    const float* W_coords = (const float*)d_in[8];
    const float* W_bond   = (const float*)d_in[9];
    const float* b_bond   = (const float*)d_in[10];
    const float* W_b0     = (const float*)d_in[11];
    const float* b_b0     = (const float*)d_in[12];
    const float* W_b1     = (const float*)d_in[13];
    const float* b_b1     = (const float*)d_in[14];
    float* out = (float*)d_out;

    float* sp2    = (float*)d_ws;                           // 262144 f32 (1 MB)
    float* coords = sp2 + (size_t)N_NODES * SDIM;           // 3072 f32
    unsigned short* Wf = (unsigned short*)(coords + 3072);  // 32768 bf16 (64 KB)
    float* bcomb  = (float*)((char*)Wf + 65536);            // 256 f32

    misc_kernel<<<169, 256, 0, stream>>>(s, W_shared, b_shared, W_b0,
                                         v, p, W_coords,
                                         W_bond, b_bond, b_b0,
                                         sp2, coords, Wf, bcomb);
    edge_mfma_kernel<<<N_PAIRS / PB, 256, 0, stream>>>(sp2, coords, e, Wf, bcomb,
                                                       W_b0, W_b1, b_b1, out);
}

// Round 4
// 29.997 us; speedup vs baseline: 4.8424x; 2.0777x over previous
//
#include <hip/hip_runtime.h>
#include <hip/hip_bf16.h>

// Sizes (fixed by the reference)
#define N_NODES 1024
#define NUM_MOL 32
#define ATOMS 32
#define SDIM 256
#define VDIM 64
#define EDIM 128
#define NBT 5
#define EDGES_PER_MOL (ATOMS * (ATOMS - 1))        // 992
#define PAIRS_PER_MOL (ATOMS * (ATOMS - 1) / 2)    // 496
#define N_PAIRS (NUM_MOL * PAIRS_PER_MOL)          // 15872

typedef __attribute__((ext_vector_type(8))) short bf16x8;
typedef __attribute__((ext_vector_type(4))) float f32x4;

__device__ __forceinline__ unsigned short f2bf(float x) {
    union { float f; unsigned int u; } v; v.f = x;
    unsigned int r = v.u + 0x7fffu + ((v.u >> 16) & 1u);
    return (unsigned short)(r >> 16);
}

__device__ __forceinline__ bf16x8 pack8(const float4& x0, const float4& x1) {
    bf16x8 r;
    r[0] = (short)f2bf(x0.x); r[1] = (short)f2bf(x0.y);
    r[2] = (short)f2bf(x0.z); r[3] = (short)f2bf(x0.w);
    r[4] = (short)f2bf(x1.x); r[5] = (short)f2bf(x1.y);
    r[6] = (short)f2bf(x1.z); r[7] = (short)f2bf(x1.w);
    return r;
}

// ---------------------------------------------------------------------------
// misc kernel, grid = 129 blocks:
//  bid 0..63  : node MFMA: sp2 = silu(s @ Ws + bs) @ Wb0[0:256,:]  (16 rows/blk)
//  bid 64..95 : coords = center_per_mol(p + v @ W_coords)
//  bid 96..127: W_comb = 0.5*(W_bond @ W_b0) -> bf16 MFMA B-frag order (4 rows/blk)
//  bid 128    : b_comb = b_bond @ W_b0 + b_b0
// ---------------------------------------------------------------------------
__global__ __launch_bounds__(256) void misc_kernel(
    const float* __restrict__ s, const float* __restrict__ Ws,
    const float* __restrict__ bs, const float* __restrict__ Wb0,
    const float* __restrict__ v, const float* __restrict__ p,
    const float* __restrict__ Wc,
    const float* __restrict__ Wbond, const float* __restrict__ bbond,
    const float* __restrict__ bb0,
    float* __restrict__ sp2, float* __restrict__ coords,
    unsigned short* __restrict__ Wf, float* __restrict__ bcomb)
{
    __shared__ __align__(16) float smem[4096];   // 16 KB union
    const int t   = threadIdx.x;
    const int bid = blockIdx.x;

    if (bid < 64) {
        // ---------------- node: MFMA pipeline ----------------
        unsigned short* s2u = (unsigned short*)smem;   // [16][256] bf16, swizzled
        const int w  = t >> 6, l = t & 63;
        const int kg = l >> 4, lr = l & 15;
        const int r0 = bid * 16;

        // A1 fragments straight from s (f32 -> bf16)
        bf16x8 a[8];
        const float* srow = s + (size_t)(r0 + lr) * SDIM + kg * 8;
#pragma unroll
        for (int kt = 0; kt < 8; ++kt) {
            const float4 x0 = *(const float4*)(srow + kt * 32);
            const float4 x1 = *(const float4*)(srow + kt * 32 + 4);
            a[kt] = pack8(x0, x1);
        }

        // GEMM1: acc = s @ Ws  (wave w covers cols 64w..64w+63)
        f32x4 acc[4];
#pragma unroll
        for (int q = 0; q < 4; ++q) {
            acc[q][0] = 0.f; acc[q][1] = 0.f; acc[q][2] = 0.f; acc[q][3] = 0.f;
            const int n = (w * 4 + q) * 16 + lr;
            const float* wcol = Ws + n;
#pragma unroll
            for (int kt = 0; kt < 8; ++kt) {
                const int kbase = kt * 32 + kg * 8;
                bf16x8 bf;
#pragma unroll
                for (int e2 = 0; e2 < 8; ++e2)
                    bf[e2] = (short)f2bf(wcol[(size_t)(kbase + e2) * SDIM]);
                acc[q] = __builtin_amdgcn_mfma_f32_16x16x32_bf16(a[kt], bf, acc[q], 0, 0, 0);
            }
        }

        // bias + silu -> bf16 LDS (XOR-swizzled)
#pragma unroll
        for (int q = 0; q < 4; ++q) {
            const int n = (w * 4 + q) * 16 + lr;
            const float bsv = bs[n];
#pragma unroll
            for (int j = 0; j < 4; ++j) {
                const int row = kg * 4 + j;
                const float x = acc[q][j] + bsv;
                const float sl = x / (1.f + __expf(-x));
                s2u[(row * 256 + n) ^ ((row & 7) << 3)] = f2bf(sl);
            }
        }
        __syncthreads();

        // A2 fragments from LDS
#pragma unroll
        for (int kt = 0; kt < 8; ++kt) {
            const int idx = (lr * 256 + kt * 32 + kg * 8) ^ ((lr & 7) << 3);
            a[kt] = *(const bf16x8*)&s2u[idx];
        }

        // GEMM2: sp2 = s' @ Wb0 (no bias)
#pragma unroll
        for (int q = 0; q < 4; ++q) {
            acc[q][0] = 0.f; acc[q][1] = 0.f; acc[q][2] = 0.f; acc[q][3] = 0.f;
            const int n = (w * 4 + q) * 16 + lr;
            const float* wcol = Wb0 + n;
#pragma unroll
            for (int kt = 0; kt < 8; ++kt) {
                const int kbase = kt * 32 + kg * 8;
                bf16x8 bf;
#pragma unroll
                for (int e2 = 0; e2 < 8; ++e2)
                    bf[e2] = (short)f2bf(wcol[(size_t)(kbase + e2) * SDIM]);
                acc[q] = __builtin_amdgcn_mfma_f32_16x16x32_bf16(a[kt], bf, acc[q], 0, 0, 0);
            }
        }
#pragma unroll
        for (int q = 0; q < 4; ++q) {
            const int n = (w * 4 + q) * 16 + lr;
#pragma unroll
            for (int j = 0; j < 4; ++j) {
                const int row = kg * 4 + j;
                sp2[(size_t)(r0 + row) * SDIM + n] = acc[q][j];
            }
        }

    } else if (bid < 96) {
        // ---------------- coords ----------------
        const int mol = bid - 64;
        float* cl   = smem;            // [32][3]
        float* mean = smem + 100;
        if (t < ATOMS * 3) {
            const int a = t / 3, dim = t % 3;
            const int node = mol * ATOMS + a;
            const float* vv = v + (size_t)node * 3 * VDIM + dim * VDIM;
            float acc = 0.f;
#pragma unroll 8
            for (int k = 0; k < VDIM; ++k) acc += vv[k] * Wc[k];
            cl[a * 3 + dim] = p[node * 3 + dim] + acc;
        }
        __syncthreads();
        if (t < 3) {
            float sum = 0.f;
            for (int a = 0; a < ATOMS; ++a) sum += cl[a * 3 + t];
            mean[t] = sum * (1.f / ATOMS);
        }
        __syncthreads();
        if (t < ATOMS * 3) {
            const int a = t / 3, dim = t % 3;
            coords[(mol * ATOMS + a) * 3 + dim] = cl[a * 3 + dim] - mean[dim];
        }

    } else if (bid < 128) {
        // ---------------- prep: W_comb -> MFMA B fragments (4 rows/block) ----
        float (*wb)[SDIM] = (float (*)[SDIM])smem;
        const int r0 = (bid - 96) * 4;
        for (int r = 0; r < 4; ++r) wb[r][t] = Wbond[(r0 + r) * SDIM + t];
        __syncthreads();

        float acc[4];
#pragma unroll
        for (int r = 0; r < 4; ++r) acc[r] = 0.f;
        for (int c = 0; c < SDIM; c += 4) {
            const float w0 = Wb0[(c + 0) * SDIM + t];
            const float w1 = Wb0[(c + 1) * SDIM + t];
            const float w2 = Wb0[(c + 2) * SDIM + t];
            const float w3 = Wb0[(c + 3) * SDIM + t];
#pragma unroll
            for (int r = 0; r < 4; ++r) {
                const float4 wv = *(const float4*)&wb[r][c];
                acc[r] += wv.x * w0 + wv.y * w1 + wv.z * w2 + wv.w * w3;
            }
        }
        const int nt = t >> 4;
#pragma unroll
        for (int r = 0; r < 4; ++r) {
            const int k = r0 + r;
            const int kt = k >> 5, g = (k >> 3) & 3, eidx = k & 7;
            const int lane = (t & 15) + 16 * g;
            Wf[((size_t)((nt * 4 + kt) * 64 + lane)) * 8 + eidx] = f2bf(0.5f * acc[r]);
        }
    } else {
        // ---------------- prep: b_comb ----------------
        float acc = bb0[t];
#pragma unroll 8
        for (int m = 0; m < SDIM; ++m) acc += bbond[m] * Wb0[m * SDIM + t];
        bcomb[t] = acc;
    }
}

// ---------------------------------------------------------------------------
// Edge kernel: block = 16 pairs, 256 threads = 4 waves.
// e_sym staged ONCE per block into bf16 LDS (swizzled); all 4 waves read
// A-frags via ds_read_b128. Wave w covers cols [64w,64w+64).
// ---------------------------------------------------------------------------
#define PB 16
__global__ __launch_bounds__(256) void edge_mfma_kernel(
    const float* __restrict__ sp2, const float* __restrict__ coords,
    const float* __restrict__ e, const unsigned short* __restrict__ Wf,
    const float* __restrict__ bcomb, const float* __restrict__ Wb0,
    const float* __restrict__ Wb1, const float* __restrict__ bb1,
    float* __restrict__ out)
{
    __shared__ __align__(16) float spsum[PB][260];        // 16.6 KB
    __shared__ __align__(16) unsigned short esym[PB * EDIM]; // 4 KB bf16, swizzled
    __shared__ float wb1s[SDIM * NBT];                    // 5 KB
    __shared__ float bb1s[8];
    __shared__ int   ksh[PB], krevsh[PB], ish[PB], jsh[PB];
    __shared__ float dsh[PB];

    const int t  = threadIdx.x;
    const int P0 = blockIdx.x * PB;

    // ---- stage W_b1 + b_b1 into LDS; decode pairs ----
    for (int idx = t; idx < SDIM * NBT; idx += 256) wb1s[idx] = Wb1[idx];
    if (t < NBT) bb1s[t] = bb1[t];
    if (t < PB) {
        const int P   = P0 + t;
        const int mol = P / PAIRS_PER_MOL;
        const int p   = P - mol * PAIRS_PER_MOL;
        int jj = (int)((63.0f - sqrtf((float)(3969 - 8 * p))) * 0.5f);
        if (jj < 0) jj = 0;
        if (jj > 30) jj = 30;
        while (jj > 0 && (63 * jj - jj * jj) / 2 > p) --jj;
        while (jj < 30 && (63 * (jj + 1) - (jj + 1) * (jj + 1)) / 2 <= p) ++jj;
        const int Ojj = (63 * jj - jj * jj) / 2;
        const int ii  = jj + 1 + (p - Ojj);
        const int q    = jj * 31 + (ii - 1);
        const int qrev = ii * 31 + jj;
        ksh[t]    = mol * EDGES_PER_MOL + q;
        krevsh[t] = mol * EDGES_PER_MOL + qrev;
        const int i = mol * ATOMS + ii, j = mol * ATOMS + jj;
        ish[t] = i; jsh[t] = j;
        const float dx = coords[i * 3 + 0] - coords[j * 3 + 0];
        const float dy = coords[i * 3 + 1] - coords[j * 3 + 1];
        const float dz = coords[i * 3 + 2] - coords[j * 3 + 2];
        dsh[t] = dx * dx + dy * dy + dz * dz;
    }
    __syncthreads();

    // ---- stage e_sym (bf16, swizzled) + spsum fill, one pass ----
    {
        const int r  = t >> 4;
        const int c8 = (t & 15) * 8;          // e_sym cols
        const float* ek  = e + (size_t)ksh[r] * EDIM + c8;
        const float* ekr = e + (size_t)krevsh[r] * EDIM + c8;
        const float4 x0 = *(const float4*)(ek);
        const float4 x1 = *(const float4*)(ek + 4);
        const float4 y0 = *(const float4*)(ekr);
        const float4 y1 = *(const float4*)(ekr + 4);

        const int c0 = (t & 15) * 4;          // spsum cols
        const float* ai = sp2 + (size_t)ish[r] * SDIM;
        const float* aj = sp2 + (size_t)jsh[r] * SDIM;
        const float* w2 = Wb0 + (size_t)SDIM * SDIM;   // row 256 of W_b0
        const float d = dsh[r];
#pragma unroll
        for (int i = 0; i < 4; ++i) {
            const int c = c0 + 64 * i;
            const float4 a4 = *(const float4*)(ai + c);
            const float4 b4 = *(const float4*)(aj + c);
            const float4 w4 = *(const float4*)(w2 + c);
            const float4 g4 = *(const float4*)(bcomb + c);
            float4 rv;
            rv.x = a4.x + b4.x + d * w4.x + g4.x;
            rv.y = a4.y + b4.y + d * w4.y + g4.y;
            rv.z = a4.z + b4.z + d * w4.z + g4.z;
            rv.w = a4.w + b4.w + d * w4.w + g4.w;
            *(float4*)&spsum[r][c] = rv;
        }

        float4 sx, sy;
        sx.x = x0.x + y0.x; sx.y = x0.y + y0.y; sx.z = x0.z + y0.z; sx.w = x0.w + y0.w;
        sy.x = x1.x + y1.x; sy.y = x1.y + y1.y; sy.z = x1.z + y1.z; sy.w = x1.w + y1.w;
        const int idx = (r * EDIM + c8) ^ ((r & 7) << 3);
        *(bf16x8*)&esym[idx] = pack8(sx, sy);
    }
    __syncthreads();

    const int w = t >> 6, l = t & 63;
    const int kg = l >> 4, lr = l & 15;

    // ---- A fragments from LDS (swizzled b128 reads) ----
    bf16x8 afrag[4];
#pragma unroll
    for (int kt = 0; kt < 4; ++kt) {
        const int idx = (lr * EDIM + kt * 32 + kg * 8) ^ ((lr & 7) << 3);
        afrag[kt] = *(const bf16x8*)&esym[idx];
    }

    // ---- MFMA: wave w covers col tiles nt = 4w .. 4w+3 ----
    const bf16x8* wfp = (const bf16x8*)Wf;
    f32x4 acc[4];
#pragma unroll
    for (int q = 0; q < 4; ++q) {
        acc[q][0] = 0.f; acc[q][1] = 0.f; acc[q][2] = 0.f; acc[q][3] = 0.f;
        const int nt = w * 4 + q;
        const bf16x8 b0 = wfp[(nt * 4 + 0) * 64 + l];
        const bf16x8 b1 = wfp[(nt * 4 + 1) * 64 + l];
        const bf16x8 b2 = wfp[(nt * 4 + 2) * 64 + l];
        const bf16x8 b3 = wfp[(nt * 4 + 3) * 64 + l];
        acc[q] = __builtin_amdgcn_mfma_f32_16x16x32_bf16(afrag[0], b0, acc[q], 0, 0, 0);
        acc[q] = __builtin_amdgcn_mfma_f32_16x16x32_bf16(afrag[1], b1, acc[q], 0, 0, 0);
        acc[q] = __builtin_amdgcn_mfma_f32_16x16x32_bf16(afrag[2], b2, acc[q], 0, 0, 0);
        acc[q] = __builtin_amdgcn_mfma_f32_16x16x32_bf16(afrag[3], b3, acc[q], 0, 0, 0);
    }

    // ---- epilogue: h = silu(acc + spsum) back into spsum ----
#pragma unroll
    for (int q = 0; q < 4; ++q) {
        const int n = (w * 4 + q) * 16 + lr;
#pragma unroll
        for (int j = 0; j < 4; ++j) {
            const int r = kg * 4 + j;
            const float x = acc[q][j] + spsum[r][n];
            spsum[r][n] = x / (1.f + __expf(-x));
        }
    }
    __syncthreads();

    // ---- final: out = h @ W_b1 + b_b1 ; 2 threads per (pair, bondtype) ----
    if (t < PB * NBT * 2) {
        const int task = t >> 1, half = t & 1;
        const int r  = task / NBT;
        const int tt = task - r * NBT;
        float a = half ? 0.f : bb1s[tt];
        const int base = half * 32;            // float4 index offset
#pragma unroll 4
        for (int cc = 0; cc < 32; ++cc) {
            const int c4 = base + ((cc + task) & 31);
            const int c  = c4 * 4;
            const float4 hv = *(const float4*)&spsum[r][c];
            a += hv.x * wb1s[(c + 0) * NBT + tt] + hv.y * wb1s[(c + 1) * NBT + tt] +
                 hv.z * wb1s[(c + 2) * NBT + tt] + hv.w * wb1s[(c + 3) * NBT + tt];
        }
        a += __shfl_xor(a, 1);
        if (!half) {
            out[(size_t)ksh[r] * NBT + tt]    = a;
            out[(size_t)krevsh[r] * NBT + tt] = a;
        }
    }
}

// ---------------------------------------------------------------------------
extern "C" void kernel_launch(void* const* d_in, const int* in_sizes, int n_in,
                              void* d_out, int out_size, void* d_ws, size_t ws_size,
                              hipStream_t stream)
{
    const float* s        = (const float*)d_in[0];
    const float* v        = (const float*)d_in[1];
    const float* p        = (const float*)d_in[2];
    const float* e        = (const float*)d_in[3];
    const float* W_shared = (const float*)d_in[6];
    const float* b_shared = (const float*)d_in[7];
    const float* W_coords = (const float*)d_in[8];
    const float* W_bond   = (const float*)d_in[9];
    const float* b_bond   = (const float*)d_in[10];
    const float* W_b0     = (const float*)d_in[11];
    const float* b_b0     = (const float*)d_in[12];
    const float* W_b1     = (const float*)d_in[13];
    const float* b_b1     = (const float*)d_in[14];
    float* out = (float*)d_out;

    float* sp2    = (float*)d_ws;                           // 262144 f32 (1 MB)
    float* coords = sp2 + (size_t)N_NODES * SDIM;           // 3072 f32
    unsigned short* Wf = (unsigned short*)(coords + 3072);  // 32768 bf16 (64 KB)
    float* bcomb  = (float*)((char*)Wf + 65536);            // 256 f32

    misc_kernel<<<129, 256, 0, stream>>>(s, W_shared, b_shared, W_b0,
                                         v, p, W_coords,
                                         W_bond, b_bond, b_b0,
                                         sp2, coords, Wf, bcomb);
    edge_mfma_kernel<<<N_PAIRS / PB, 256, 0, stream>>>(sp2, coords, e, Wf, bcomb,
                                                       W_b0, W_b1, b_b1, out);
}